// Round 10
// baseline (1158.492 us; speedup 1.0000x reference)
//
#include <hip/hip_runtime.h>

typedef _Float16 f16;
typedef _Float16 f16x8 __attribute__((ext_vector_type(8)));
typedef float    f32x4 __attribute__((ext_vector_type(4)));
typedef unsigned int u32;
typedef u32 u32x4 __attribute__((ext_vector_type(4)));

#define MFMA16(a, b, c) __builtin_amdgcn_mfma_f32_16x16x32_f16((a), (b), (c), 0, 0, 0)

#define HSZ 262144            // 512*512
#define LOGDET_C 235.2482644923962f  // 128*log(2*pi)

// ---- memory access primitives -------------------------------------------
// _n (plain): cacheable; used only on read-only inputs, virgin monotonic
//     addresses, or verified same-XCD exchange (shared L2 coherence point).
// _s (sc0 sc1): L3 coherence point; proven cross-XCD-safe (rounds 3-9).
__device__ __forceinline__ void ld16_n(u32x4& d, const f16* p) {
    asm volatile("global_load_dwordx4 %0, %1, off" : "=v"(d) : "v"(p));
}
__device__ __forceinline__ void ld16_s(u32x4& d, const f16* p) {
    asm volatile("global_load_dwordx4 %0, %1, off sc0 sc1" : "=v"(d) : "v"(p));
}
__device__ __forceinline__ void ldf_n(float& d, const float* p) {
    asm volatile("global_load_dword %0, %1, off" : "=v"(d) : "v"(p));
}
__device__ __forceinline__ void st2_n(f16* p, f16 v) {
    u32 u = (u32)__builtin_bit_cast(unsigned short, v);
    asm volatile("global_store_short %0, %1, off" :: "v"(p), "v"(u) : "memory");
}
__device__ __forceinline__ void st2_s(f16* p, f16 v) {
    u32 u = (u32)__builtin_bit_cast(unsigned short, v);
    asm volatile("global_store_short %0, %1, off sc0 sc1" :: "v"(p), "v"(u) : "memory");
}
__device__ __forceinline__ void sti_s(int* p, int v) {
    asm volatile("global_store_dword %0, %1, off sc0 sc1" :: "v"(p), "v"(v) : "memory");
}
__device__ __forceinline__ int ldi_s(const int* p) {
    int v;
    asm volatile("global_load_dword %0, %1, off sc0 sc1\ns_waitcnt vmcnt(0)"
                 : "=v"(v) : "v"(p) : "memory");
    return v;
}
// async global->LDS 16B (per-lane global src, wave-linear LDS dest)
__device__ __forceinline__ void gl16(const f16* g, char* l) {
    __builtin_amdgcn_global_load_lds(
        (const __attribute__((address_space(1))) u32*)g,
        (__attribute__((address_space(3))) u32*)l, 16, 0, 0);
}
// tanh via HW exp2+rcp: tanh(x) = 1 - 2/(exp2(x*2/ln2)+1). |err| ~1e-6.
__device__ __forceinline__ float tanh_fast(float x) {
    float e = __builtin_amdgcn_exp2f(x * 2.8853900817779268f);
    return 1.f - 2.f * __builtin_amdgcn_rcpf(e + 1.f);
}

// ---------------------------------------------------------------------------
// k_conv: conversions + small vectors; init slots=0, xcdtab=-1.
__global__ void k_conv(const float* __restrict__ x, const float* __restrict__ mask,
                       const float* __restrict__ Wih0,
                       const float* __restrict__ b_ih0, const float* __restrict__ b_hh0,
                       const float* __restrict__ Whh0, const float* __restrict__ Wih1,
                       const float* __restrict__ Whh1, const float* __restrict__ W1,
                       const float* __restrict__ W2,
                       f16* __restrict__ A, f16* __restrict__ B1,
                       float* __restrict__ biasv,
                       f16* __restrict__ Whh0h, f16* __restrict__ Wih1h,
                       f16* __restrict__ Whh1h, f16* __restrict__ W1h,
                       f16* __restrict__ W2h, f16* __restrict__ h1all,
                       int* __restrict__ slots, int* __restrict__ xcdtab)
{
    int gid = blockIdx.x * 256 + threadIdx.x;   // 0..65535
    {
        int c = gid >> 7, k = gid & 127;
        A[gid]  = (f16)(x[gid] * mask[k]);
        B1[gid] = (f16)Wih0[c * 257 + 1 + k];
    }
    if (gid < 512) {
        float s = b_ih0[gid] + b_hh0[gid];
        const float* wrow = Wih0 + gid * 257 + 129;
        for (int k = 0; k < 128; k++) s += mask[k] * wrow[k];
        biasv[gid] = s;
    }
    for (int i = gid; i < 262144; i += 65536) {
        Whh0h[i] = (f16)Whh0[i];
        Wih1h[i] = (f16)Wih1[i];
        Whh1h[i] = (f16)Whh1[i];
        h1all[i] = (f16)0.f;      // h1[t=-1]
    }
    for (int i = gid; i < 1048576; i += 65536) W1h[i] = (f16)W1[i];
    for (int i = gid; i < 524288;  i += 65536) W2h[i] = (f16)W2[i];
    if (gid < 32768) slots[gid] = 0;
    if (gid < 4096)  xcdtab[gid] = -1;
}

// ---------------------------------------------------------------------------
// k_base: base = A @ B1^T + biasv ; h0 slab0 = tanh(base)
__global__ __launch_bounds__(256) void k_base(const f16* __restrict__ A,
                                              const f16* __restrict__ B1,
                                              const float* __restrict__ biasv,
                                              float* __restrict__ base,
                                              f16* __restrict__ h0s0)
{
    __shared__ float part[4][32][32];
    int tid = threadIdx.x;
    int w = tid >> 6, l = tid & 63;
    int R0 = (blockIdx.x >> 4) * 32, C0 = (blockIdx.x & 15) * 32;
    int lr = l & 15, hi = l >> 4;

    const f16* a0p = A  + (R0 + lr) * 128 + w * 32 + hi * 8;
    const f16* b0p = B1 + (C0 + lr) * 128 + w * 32 + hi * 8;
    f16x8 a0 = *(const f16x8*)(a0p);
    f16x8 a1 = *(const f16x8*)(a0p + 16 * 128);
    f16x8 b0 = *(const f16x8*)(b0p);
    f16x8 b1 = *(const f16x8*)(b0p + 16 * 128);
    f32x4 z = {0.f, 0.f, 0.f, 0.f};
    f32x4 acc00 = MFMA16(a0, b0, z);
    f32x4 acc01 = MFMA16(a0, b1, z);
    f32x4 acc10 = MFMA16(a1, b0, z);
    f32x4 acc11 = MFMA16(a1, b1, z);
#pragma unroll
    for (int r = 0; r < 4; r++) {
        part[w][hi * 4 + r][lr]           = acc00[r];
        part[w][hi * 4 + r][16 + lr]      = acc01[r];
        part[w][16 + hi * 4 + r][lr]      = acc10[r];
        part[w][16 + hi * 4 + r][16 + lr] = acc11[r];
    }
    __syncthreads();
    int rr = tid >> 3, c0 = (tid & 7) * 4;
    int gr = R0 + rr;
#pragma unroll
    for (int cc = 0; cc < 4; cc++) {
        int gc = C0 + c0 + cc;
        float s = part[0][rr][c0 + cc] + part[1][rr][c0 + cc] +
                  part[2][rr][c0 + cc] + part[3][rr][c0 + cc] + biasv[gc];
        base[gr * 512 + gc] = s;
        h0s0[gr * 512 + gc] = (f16)tanh_fast(s);
    }
}

// ---------------------------------------------------------------------------
// Persistent recurrence kernel v6: ONE poll + ONE drain + ONE signal per
// phase. Correctness of merged signal: sigB(p+1) is issued after vmcnt(0)
// drains BOTH h0[p+1] and h1[p] stores; so pollB(p) at phase-p top implies
// peers completed phase p-1 entirely -> h0[p] AND h1[p-1] visible, and all
// their phase p-1 READS retired (vmcnt retires in-order) -> 2-slab reuse is
// race-free without barriers.
// Weight placement (fix of r8/r9 VGPR sink): Whh0 fragments (64 VGPR) in
// registers; Wih1/Whh1 in swizzled LDS (LDB) -> peak ~240 VGPR, fits.
#define RNN_PHASES(LD16x, ST2x)                                               \
    for (int p = 0; p < 128; p++) {                                           \
        const f16* H0 = h0all + (size_t)(p & PMASK) * HSZ;                    \
        const f16* H1 = h1all + (size_t)p * HSZ;                              \
        const f16* ap = H0 + (R0 + r_lo + lr) * 512 + hi * 8;                 \
        const f16* bp = H1 + (R0 + r_lo + lr) * 512 + hi * 8;                 \
        f16* H1o = h1all + (size_t)(p + 1) * HSZ;                             \
        f16* H0o = h0all + (size_t)((p + 1) & PMASK) * HSZ;                   \
        if (p) { int v; do { v = ldi_s(pollB); } while (!__all(v >= p)); }    \
        u32x4 ra0[16], ra1[16];                                               \
        float xprev[4];                                                       \
        __builtin_amdgcn_sched_barrier(0);                                    \
        _Pragma("unroll")                                                     \
        for (int f = 0; f < 16; f++) LD16x(ra0[f], ap + f * 32);              \
        _Pragma("unroll")                                                     \
        for (int f = 0; f < 16; f++) LD16x(ra1[f], bp + f * 32);              \
        _Pragma("unroll")                                                     \
        for (int r = 0; r < 4; r++) ldf_n(xprev[r], x + (outrow + r) * 128 + p); \
        asm volatile("s_waitcnt vmcnt(20)" ::: "memory");                     \
        __builtin_amdgcn_sched_barrier(0);                                    \
        f32x4 z4 = {0.f, 0.f, 0.f, 0.f};                                      \
        f32x4 a0a = z4, a0b = z4, a1a = z4, a1b = z4;                         \
        _Pragma("unroll")                                                     \
        for (int f = 0; f < 16; f += 2) {                                     \
            a0a = MFMA16(__builtin_bit_cast(f16x8, ra0[f]),   bW0[f],   a0a); \
            a0b = MFMA16(__builtin_bit_cast(f16x8, ra0[f+1]), bW0[f+1], a0b); \
        }                                                                     \
        _Pragma("unroll")                                                     \
        for (int f = 0; f < 16; f += 2) {                                     \
            a1a = MFMA16(__builtin_bit_cast(f16x8, ra0[f]),                   \
                         LDB(0, f * 32 + hi * 8), a1a);                       \
            a1b = MFMA16(__builtin_bit_cast(f16x8, ra0[f+1]),                 \
                         LDB(0, (f+1) * 32 + hi * 8), a1b);                   \
        }                                                                     \
        asm volatile("s_waitcnt vmcnt(0)" ::: "memory");                      \
        __builtin_amdgcn_sched_barrier(0);                                    \
        f32x4 acc0 = a0a + a0b;                                               \
        _Pragma("unroll")                                                     \
        for (int r = 0; r < 4; r++) {                                         \
            f16 v0 = (f16)tanh_fast(acc0[r] + basef[r] + xprev[r] * w0);      \
            ST2x(H0o + (outrow + r) * 512 + outcolg, v0);                     \
        }                                                                     \
        _Pragma("unroll")                                                     \
        for (int f = 0; f < 16; f += 2) {                                     \
            a1a = MFMA16(__builtin_bit_cast(f16x8, ra1[f]),                   \
                         LDB(1, f * 32 + hi * 8), a1a);                       \
            a1b = MFMA16(__builtin_bit_cast(f16x8, ra1[f+1]),                 \
                         LDB(1, (f+1) * 32 + hi * 8), a1b);                   \
        }                                                                     \
        f32x4 acc1 = a1a + a1b;                                               \
        _Pragma("unroll")                                                     \
        for (int r = 0; r < 4; r++) {                                         \
            f16 v1 = (f16)tanh_fast(acc1[r] + bsum);                          \
            ST2x(H1o + (outrow + r) * 512 + outcolg, v1);                     \
        }                                                                     \
        asm volatile("s_waitcnt vmcnt(0)" ::: "memory");                      \
        if (l == 0) sti_s(myB, p + 1);                                        \
    }

template<bool H0F>
__global__ __launch_bounds__(256, 1) void k_rnn(
    f16* __restrict__ h0all, f16* __restrict__ h1all,
    const f16* __restrict__ Whh0h, const f16* __restrict__ Wih1h,
    const f16* __restrict__ Whh1h,
    const float* __restrict__ base, const float* __restrict__ x,
    const float* __restrict__ Wih0, const float* __restrict__ b_ih1,
    const float* __restrict__ b_hh1, int* __restrict__ slots,
    int* __restrict__ xcdtab)
{
    constexpr int PMASK = H0F ? 255 : 1;
    __shared__ __align__(16) f16 Wl[2 * 32 * 512];   // 64KB: Wih1, Whh1 swizzled
    __shared__ int s_fast;
    __shared__ volatile int pin[7424];               // +29KB -> ~94KB: 1 wg/CU
    int tid = threadIdx.x;
    int w = tid >> 6, l = tid & 63;
    int bid = blockIdx.x;
    int sub = (bid >> 3) & 1, cj = bid >> 4;
    int cluster = (bid & 7) * 2 + sub;       // cluster-mates share bid&7
    int R0 = cluster * 32, C0 = cj * 32;
    pin[tid] = 0;                            // touch -> LDS kept

    int xcdreg;
    asm("s_getreg_b32 %0, hwreg(20, 0, 4)" : "=s"(xcdreg));  // HW_REG_XCC_ID[3:0]
    int my_xcd = xcdreg & 7;
    if (H0F && tid == 0) sti_s(xcdtab + (cluster * 16 + cj) * 16, my_xcd);

    // ---- stage Wih1/Whh1 col-slices into LDS with bank-conflict swizzle
    {
        const f16* srcs[2] = { Wih1h, Whh1h };
        for (int m = 0; m < 2; m++) {
            const f16* S = srcs[m] + (size_t)C0 * 512;
            for (int cch = tid; cch < 2048; cch += 256) {
                int col = cch >> 6, kc = cch & 63;
                f16x8 v = *(const f16x8*)(S + col * 512 + kc * 8);
                int byte = m * 32768 + col * 1024 + kc * 16;
                byte ^= (col & 7) << 4;
                *(f16x8*)((char*)Wl + byte) = v;
            }
        }
    }
    __syncthreads();

    int lr = l & 15, hi = l >> 4;
    int r_lo = (w >> 1) * 16, c_lo = (w & 1) * 16;
    int outrow = R0 + r_lo + hi * 4;
    int outcolg = C0 + c_lo + lr;
    int colL = c_lo + lr;

    // ---- Whh0 B-fragments in registers (64 VGPR; peak ~240 so no sink)
    f16x8 bW0[16];
    {
        const f16* w0p = Whh0h + (size_t)outcolg * 512 + hi * 8;
#pragma unroll
        for (int f = 0; f < 16; f++) bW0[f] = *(const f16x8*)(w0p + f * 32);
    }

    float basef[4];
#pragma unroll
    for (int r = 0; r < 4; r++) basef[r] = base[(outrow + r) * 512 + outcolg];
    float w0 = Wih0[outcolg * 257];
    float bsum = b_ih1[outcolg] + b_hh1[outcolg];

    // ---- per-wave B-slots (one signal per wave per phase)
    int wslot = cj * 4 + w;                   // 0..63 within cluster
    int* myB = slots + (cluster * 64 + wslot) * 16;
    const int* pollB = slots + (cluster * 64 + l) * 16;   // lane l -> slot l

    // ---- cluster XCD-locality verification (publishes guaranteed by
    //      1wg/CU co-residency; polling primitive is the proven sc0sc1 load)
    bool fast = false;
    if constexpr (H0F) {
        if (w == 0) {
            int v;
            do { v = (l < 16) ? ldi_s(xcdtab + (cluster * 16 + l) * 16) : 0; }
            while (__any(l < 16 && v == -1));
            int f = __all(l >= 16 || v == my_xcd);
            if (l == 0) s_fast = f;
        }
        __syncthreads();
        fast = (s_fast != 0);
    } else {
        if (tid == 0) s_fast = 0;
        __syncthreads();
    }

#define LDB(m, k0) (*(const f16x8*)((char*)Wl + \
        ((((m) * 32768 + colL * 1024 + (k0) * 2)) ^ ((colL & 7) << 4))))

    if (H0F && fast) {
        RNN_PHASES(ld16_n, st2_n)      // same-XCD: shared L2 coherence
    } else if (H0F) {
        RNN_PHASES(ld16_n, st2_s)      // virgin slabs: plain reads, L3 writes
    } else {
        RNN_PHASES(ld16_s, st2_s)      // 2-slab ring: full L3 coherence
    }
#undef LDB
}

// ---------------------------------------------------------------------------
// Phase B v3 (unchanged from round 5)
__global__ __launch_bounds__(512, 2) void k_phaseB(const f16* __restrict__ h1all,
                                                   const f16* __restrict__ W1h,
                                                   const f16* __restrict__ W2h,
                                                   const float* __restrict__ b1v,
                                                   const float* __restrict__ b2,
                                                   const float* __restrict__ x,
                                                   float* __restrict__ pcontrib)
{
    __shared__ __align__(16) char Wl[108544];
    const int OFF_W2 = 65536, OFF_HID = 98304;

    int tid = threadIdx.x;
    int wv = tid >> 6, l = tid & 63;
    int lr = l & 15, hi = l >> 4;
    int M0 = blockIdx.x * 128;

    const f16* Hrow = h1all + HSZ + (size_t)(M0 + wv * 16 + lr) * 512;
    f16x8 afrag[16];
#pragma unroll
    for (int ks = 0; ks < 16; ks++)
        afrag[ks] = *(const f16x8*)(Hrow + ks * 32 + hi * 8);

    f32x4 mc[16] = {};

    {
#pragma unroll
        for (int it = 0; it < 4; it++) {
            int idx = it * 512 + tid;
            gl16(W1h + (size_t)(idx & 31) * 512 + (idx >> 5) * 8,
                 Wl + idx * 16);
        }
#pragma unroll
        for (int it = 0; it < 2; it++) {
            int idx = it * 512 + tid;
            gl16(W2h + (size_t)(idx & 255) * 2048 + (idx >> 8) * 8,
                 Wl + OFF_W2 + idx * 16);
        }
    }

    for (int c = 0; c < 64; c++) {
        int p = c & 1;
        __syncthreads();

        if (c + 1 < 64) {
            const int nc = (c + 1) * 32, q = p ^ 1;
#pragma unroll
            for (int it = 0; it < 4; it++) {
                int idx = it * 512 + tid;
                gl16(W1h + (size_t)(nc + (idx & 31)) * 512 + (idx >> 5) * 8,
                     Wl + q * 32768 + idx * 16);
            }
#pragma unroll
            for (int it = 0; it < 2; it++) {
                int idx = it * 512 + tid;
                gl16(W2h + (size_t)(idx & 255) * 2048 + nc + (idx >> 8) * 8,
                     Wl + OFF_W2 + q * 16384 + idx * 16);
            }
        }

        {
            f32x4 s3a = {0.f, 0.f, 0.f, 0.f}, s3b = s3a;
#pragma unroll
            for (int ks = 0; ks < 16; ks++) {
                f16x8 wb0 = *(const f16x8*)(Wl + p * 32768 +
                                            ((ks * 4 + hi) * 32 + lr) * 16);
                f16x8 wb1 = *(const f16x8*)(Wl + p * 32768 +
                                            ((ks * 4 + hi) * 32 + 16 + lr) * 16);
                s3a = MFMA16(afrag[ks], wb0, s3a);
                s3b = MFMA16(afrag[ks], wb1, s3b);
            }
            float bb0 = b1v[c * 32 + lr];
            float bb1 = b1v[c * 32 + 16 + lr];
#pragma unroll
            for (int r = 0; r < 4; r++) {
                int lrow = wv * 16 + hi * 4 + r;
                *(f16*)(Wl + OFF_HID + (lrow * 40 + lr) * 2) =
                    (f16)fmaxf(s3a[r] + bb0, 0.f);
                *(f16*)(Wl + OFF_HID + (lrow * 40 + 16 + lr) * 2) =
                    (f16)fmaxf(s3b[r] + bb1, 0.f);
            }
        }
        __syncthreads();

        {
            f16x8 a = *(const f16x8*)(Wl + OFF_HID +
                                      ((wv * 16 + lr) * 40 + hi * 8) * 2);
#pragma unroll
            for (int cf = 0; cf < 16; cf++) {
                f16x8 b = *(const f16x8*)(Wl + OFF_W2 + p * 16384 +
                                          (hi * 256 + cf * 16 + lr) * 16);
                mc[cf] = MFMA16(a, b, mc[cf]);
            }
        }
    }

    float quad[4] = {}, ls[4] = {}, xt[4];
#pragma unroll
    for (int r = 0; r < 4; r++) {
        int m = M0 + wv * 16 + hi * 4 + r;
        xt[r] = x[(m & 511) * 128 + (m >> 9)];
    }
#pragma unroll
    for (int cf = 0; cf < 8; cf++) {
        int cc = cf * 16 + lr;
        float bm = b2[cc], bc = b2[128 + cc];
#pragma unroll
        for (int r = 0; r < 4; r++) {
            float mean = mc[cf][r] + bm;
            float cov  = mc[cf + 8][r] + bc;
            float sp = log1pf(expf(-fabsf(cov))) + fmaxf(cov, 0.f);
            float d = xt[r] - mean;
            quad[r] += d * d * sp;
            ls[r] += logf(sp);
        }
    }
#pragma unroll
    for (int mm = 1; mm < 16; mm <<= 1)
#pragma unroll
        for (int r = 0; r < 4; r++) {
            quad[r] += __shfl_xor(quad[r], mm, 64);
            ls[r]   += __shfl_xor(ls[r], mm, 64);
        }
    if (lr == 0) {
#pragma unroll
        for (int r = 0; r < 4; r++) {
            int m = M0 + wv * 16 + hi * 4 + r;
            pcontrib[m] = -0.5f * (LOGDET_C + quad[r]) - 0.5f * ls[r];
        }
    }
}

// ---------------------------------------------------------------------------
__global__ void k_fin(const f16* __restrict__ h1last,
                      const float* __restrict__ pcontrib, float* __restrict__ out)
{
    int gid = blockIdx.x * 256 + threadIdx.x;
    for (int i = gid; i < HSZ; i += 131072) out[i] = (float)h1last[i];
    if (gid < 512) {
        float s = 0.f;
        for (int tt = 0; tt < 128; tt++) s += pcontrib[tt * 512 + gid];
        out[HSZ + gid] = s;
    }
}

// ---------------------------------------------------------------------------
extern "C" void kernel_launch(void* const* d_in, const int* in_sizes, int n_in,
                              void* d_out, int out_size, void* d_ws, size_t ws_size,
                              hipStream_t stream) {
    const float* x     = (const float*)d_in[0];
    const float* mask  = (const float*)d_in[1];
    const float* Wih0  = (const float*)d_in[2];
    const float* Whh0  = (const float*)d_in[3];
    const float* b_ih0 = (const float*)d_in[4];
    const float* b_hh0 = (const float*)d_in[5];
    const float* Wih1  = (const float*)d_in[6];
    const float* Whh1  = (const float*)d_in[7];
    const float* b_ih1 = (const float*)d_in[8];
    const float* b_hh1 = (const float*)d_in[9];
    const float* W1    = (const float*)d_in[10];
    const float* b1    = (const float*)d_in[11];
    const float* W2    = (const float*)d_in[12];
    const float* b2    = (const float*)d_in[13];

    char* ws = (char*)d_ws;
    size_t off = 0;
    auto take = [&](size_t bytes) { char* p = ws + off; off += (bytes + 255) & ~(size_t)255; return p; };
    float* base    = (float*)take(512 * 512 * 4);
    f16* Whh0h     = (f16*)take(HSZ * 2);
    f16* Wih1h     = (f16*)take(HSZ * 2);
    f16* Whh1h     = (f16*)take(HSZ * 2);
    f16* W1h       = (f16*)take(1048576 * 2);
    f16* W2h       = (f16*)take(524288 * 2);
    f16* h0buf     = (f16*)take(2 * HSZ * 2);
    f16* h1all     = (f16*)take((size_t)129 * HSZ * 2);
    float* pcontrib= (float*)take(128 * 512 * 4);
    f16* A         = (f16*)take(65536 * 2);
    f16* B1        = (f16*)take(65536 * 2);
    float* biasv   = (float*)take(512 * 4);
    int* slots     = (int*)take(32768 * 4);
    int* xcdtab    = (int*)take(4096 * 4);
    if (off > ws_size) return;

    // Optional monotonic h0 slabs (66 MB): enables cached/virgin h0 reads.
    const size_t h0all_bytes = (size_t)129 * HSZ * 2;
    bool big = (off + h0all_bytes + 256 <= ws_size);
    f16* h0all = big ? (f16*)take(h0all_bytes) : h0buf;

    k_conv<<<256, 256, 0, stream>>>(x, mask, Wih0, b_ih0, b_hh0, Whh0, Wih1, Whh1,
                                    W1, W2, A, B1, biasv, Whh0h, Wih1h, Whh1h,
                                    W1h, W2h, h1all, slots, xcdtab);
    k_base<<<256, 256, 0, stream>>>(A, B1, biasv, base, h0all);
    if (big)
        k_rnn<true><<<256, 256, 0, stream>>>(h0all, h1all, Whh0h, Wih1h, Whh1h,
                                             base, x, Wih0, b_ih1, b_hh1, slots,
                                             xcdtab);
    else
        k_rnn<false><<<256, 256, 0, stream>>>(h0all, h1all, Whh0h, Wih1h, Whh1h,
                                              base, x, Wih0, b_ih1, b_hh1, slots,
                                              xcdtab);
    k_phaseB<<<512, 512, 0, stream>>>(h1all, W1h, W2h, b1, b2, x, pcontrib);
    k_fin<<<512, 256, 0, stream>>>(h1all + (size_t)128 * HSZ, pcontrib, (float*)d_out);
}

// Round 11
// 747.344 us; speedup vs baseline: 1.5501x; 1.5501x over previous
//
#include <hip/hip_runtime.h>

typedef _Float16 f16;
typedef _Float16 f16x8 __attribute__((ext_vector_type(8)));
typedef float    f32x4 __attribute__((ext_vector_type(4)));
typedef unsigned int u32;
typedef u32 u32x4 __attribute__((ext_vector_type(4)));

#define MFMA16(a, b, c) __builtin_amdgcn_mfma_f32_16x16x32_f16((a), (b), (c), 0, 0, 0)

#define HSZ 262144            // 512*512
#define LOGDET_C 235.2482644923962f  // 128*log(2*pi)

// ---- memory access primitives -------------------------------------------
__device__ __forceinline__ void ld16_s(u32x4& d, const f16* p) {
    asm volatile("global_load_dwordx4 %0, %1, off sc0 sc1" : "=v"(d) : "v"(p));
}
__device__ __forceinline__ void ldf_n(float& d, const float* p) {
    asm volatile("global_load_dword %0, %1, off" : "=v"(d) : "v"(p));
}
__device__ __forceinline__ void st2_n(f16* p, f16 v) {
    u32 u = (u32)__builtin_bit_cast(unsigned short, v);
    asm volatile("global_store_short %0, %1, off" :: "v"(p), "v"(u) : "memory");
}
__device__ __forceinline__ void st2_s(f16* p, f16 v) {
    u32 u = (u32)__builtin_bit_cast(unsigned short, v);
    asm volatile("global_store_short %0, %1, off sc0 sc1" :: "v"(p), "v"(u) : "memory");
}
__device__ __forceinline__ void sti_s(int* p, int v) {
    asm volatile("global_store_dword %0, %1, off sc0 sc1" :: "v"(p), "v"(v) : "memory");
}
__device__ __forceinline__ int ldi_s(const int* p) {
    int v;
    asm volatile("global_load_dword %0, %1, off sc0 sc1\ns_waitcnt vmcnt(0)"
                 : "=v"(v) : "v"(p) : "memory");
    return v;
}
// async global->LDS 16B (per-lane global src, wave-linear LDS dest)
__device__ __forceinline__ void gl16(const f16* g, char* l) {
    __builtin_amdgcn_global_load_lds(
        (const __attribute__((address_space(1))) u32*)g,
        (__attribute__((address_space(3))) u32*)l, 16, 0, 0);
}
// tanh via HW exp2+rcp: tanh(x) = 1 - 2/(exp2(x*2/ln2)+1). |err| ~1e-6.
__device__ __forceinline__ float tanh_fast(float x) {
    float e = __builtin_amdgcn_exp2f(x * 2.8853900817779268f);
    return 1.f - 2.f * __builtin_amdgcn_rcpf(e + 1.f);
}

// ---------------------------------------------------------------------------
// k_conv: conversions + small vectors; init slots=0, xcdtab=-1.
__global__ void k_conv(const float* __restrict__ x, const float* __restrict__ mask,
                       const float* __restrict__ Wih0,
                       const float* __restrict__ b_ih0, const float* __restrict__ b_hh0,
                       const float* __restrict__ Whh0, const float* __restrict__ Wih1,
                       const float* __restrict__ Whh1, const float* __restrict__ W1,
                       const float* __restrict__ W2,
                       f16* __restrict__ A, f16* __restrict__ B1,
                       float* __restrict__ biasv,
                       f16* __restrict__ Whh0h, f16* __restrict__ Wih1h,
                       f16* __restrict__ Whh1h, f16* __restrict__ W1h,
                       f16* __restrict__ W2h, f16* __restrict__ h1all,
                       int* __restrict__ slots, int* __restrict__ xcdtab)
{
    int gid = blockIdx.x * 256 + threadIdx.x;   // 0..65535
    {
        int c = gid >> 7, k = gid & 127;
        A[gid]  = (f16)(x[gid] * mask[k]);
        B1[gid] = (f16)Wih0[c * 257 + 1 + k];
    }
    if (gid < 512) {
        float s = b_ih0[gid] + b_hh0[gid];
        const float* wrow = Wih0 + gid * 257 + 129;
        for (int k = 0; k < 128; k++) s += mask[k] * wrow[k];
        biasv[gid] = s;
    }
    for (int i = gid; i < 262144; i += 65536) {
        Whh0h[i] = (f16)Whh0[i];
        Wih1h[i] = (f16)Wih1[i];
        Whh1h[i] = (f16)Whh1[i];
        h1all[i] = (f16)0.f;      // h1[t=-1]
    }
    for (int i = gid; i < 1048576; i += 65536) W1h[i] = (f16)W1[i];
    for (int i = gid; i < 524288;  i += 65536) W2h[i] = (f16)W2[i];
    if (gid < 32768) slots[gid] = 0;
    if (gid < 4096)  xcdtab[gid] = -1;
}

// ---------------------------------------------------------------------------
// k_base: base = A @ B1^T + biasv ; h0 slab0 = tanh(base)
__global__ __launch_bounds__(256) void k_base(const f16* __restrict__ A,
                                              const f16* __restrict__ B1,
                                              const float* __restrict__ biasv,
                                              float* __restrict__ base,
                                              f16* __restrict__ h0s0)
{
    __shared__ float part[4][32][32];
    int tid = threadIdx.x;
    int w = tid >> 6, l = tid & 63;
    int R0 = (blockIdx.x >> 4) * 32, C0 = (blockIdx.x & 15) * 32;
    int lr = l & 15, hi = l >> 4;

    const f16* a0p = A  + (R0 + lr) * 128 + w * 32 + hi * 8;
    const f16* b0p = B1 + (C0 + lr) * 128 + w * 32 + hi * 8;
    f16x8 a0 = *(const f16x8*)(a0p);
    f16x8 a1 = *(const f16x8*)(a0p + 16 * 128);
    f16x8 b0 = *(const f16x8*)(b0p);
    f16x8 b1 = *(const f16x8*)(b0p + 16 * 128);
    f32x4 z = {0.f, 0.f, 0.f, 0.f};
    f32x4 acc00 = MFMA16(a0, b0, z);
    f32x4 acc01 = MFMA16(a0, b1, z);
    f32x4 acc10 = MFMA16(a1, b0, z);
    f32x4 acc11 = MFMA16(a1, b1, z);
#pragma unroll
    for (int r = 0; r < 4; r++) {
        part[w][hi * 4 + r][lr]           = acc00[r];
        part[w][hi * 4 + r][16 + lr]      = acc01[r];
        part[w][16 + hi * 4 + r][lr]      = acc10[r];
        part[w][16 + hi * 4 + r][16 + lr] = acc11[r];
    }
    __syncthreads();
    int rr = tid >> 3, c0 = (tid & 7) * 4;
    int gr = R0 + rr;
#pragma unroll
    for (int cc = 0; cc < 4; cc++) {
        int gc = C0 + c0 + cc;
        float s = part[0][rr][c0 + cc] + part[1][rr][c0 + cc] +
                  part[2][rr][c0 + cc] + part[3][rr][c0 + cc] + biasv[gc];
        base[gr * 512 + gc] = s;
        h0s0[gr * 512 + gc] = (f16)tanh_fast(s);
    }
}

// ---------------------------------------------------------------------------
// Persistent recurrence kernel v7: r9's split-signal skeleton + LDS h-staging.
//   - h tiles staged once per wg via global_load_lds (plain cacheable; safe on
//     virgin monotonic slabs), pre-swizzled source chunks so linear LDS dest
//     equals the XOR-swizzled layout -> conflict-free ds_read_b128.
//   - per-wave slots; sigB right after h0 store-drain (keeps peers' h0 chain
//     running while we do h1); sigA after h1 store-drain.
//   - all spin loops throttled with s_sleep(1).
//   - LDS: 64KB weights (Wih1/Whh1 swizzled) + 32KB h0s + 32KB h1s = 128KB
//     -> 1 wg/CU guaranteed. Whh0 fragments in VGPR (64 regs).
#define LDH(off, f) (*(const f16x8*)((char*)Wl + (off) + lrowB + \
        ((((f) * 64 + hi16)) ^ lswz)))
#define LDB(m, f) (*(const f16x8*)((char*)Wl + \
        (((m) * 32768 + colL * 1024 + (f) * 64 + hi16) ^ cswz)))

#define RNN_STAGED(ST2x)                                                      \
    for (int p = 0; p < 128; p++) {                                           \
        const f16* H0 = h0all + (size_t)(p & PMASK) * HSZ;                    \
        const f16* H1 = h1all + (size_t)p * HSZ;                              \
        f16* H1o = h1all + (size_t)(p + 1) * HSZ;                             \
        f16* H0o = h0all + (size_t)((p + 1) & PMASK) * HSZ;                   \
        float xprev[4];                                                       \
        _Pragma("unroll")                                                     \
        for (int r = 0; r < 4; r++) ldf_n(xprev[r], x + (outrow + r) * 128 + p); \
        if (p) { int v; for (;;) { v = ldi_s(pollB); if (__all(v >= p)) break; \
                                   __builtin_amdgcn_s_sleep(1); } }           \
        _Pragma("unroll")                                                     \
        for (int i = 0; i < 8; i++) {                                         \
            int rr = w * 8 + i;                                               \
            gl16(H0 + (size_t)(R0 + rr) * 512 + ((l ^ (rr & 7)) * 8),         \
                 (char*)Wl + OFF_H0S + rr * 1024);                            \
        }                                                                     \
        asm volatile("s_waitcnt vmcnt(0)" ::: "memory");                      \
        __syncthreads();                                                      \
        f32x4 z4 = {0.f, 0.f, 0.f, 0.f};                                      \
        f32x4 a0a = z4, a0b = z4, a1a = z4, a1b = z4;                         \
        _Pragma("unroll")                                                     \
        for (int f = 0; f < 16; f += 2) {                                     \
            f16x8 A0 = LDH(OFF_H0S, f);                                       \
            f16x8 A1 = LDH(OFF_H0S, f + 1);                                   \
            a0a = MFMA16(A0, bW0[f],     a0a);                                \
            a0b = MFMA16(A1, bW0[f + 1], a0b);                                \
            a1a = MFMA16(A0, LDB(0, f),     a1a);                             \
            a1b = MFMA16(A1, LDB(0, f + 1), a1b);                             \
        }                                                                     \
        f32x4 acc0 = a0a + a0b;                                               \
        _Pragma("unroll")                                                     \
        for (int r = 0; r < 4; r++) {                                         \
            f16 v0 = (f16)tanh_fast(acc0[r] + basef[r] + xprev[r] * w0);      \
            ST2x(H0o + (outrow + r) * 512 + outcolg, v0);                     \
        }                                                                     \
        asm volatile("s_waitcnt vmcnt(0)" ::: "memory");                      \
        if (l == 0) sti_s(myB, p + 1);                                        \
        if (p) { int v; for (;;) { v = ldi_s(pollA); if (__all(v >= p)) break; \
                                   __builtin_amdgcn_s_sleep(1); } }           \
        _Pragma("unroll")                                                     \
        for (int i = 0; i < 8; i++) {                                         \
            int rr = w * 8 + i;                                               \
            gl16(H1 + (size_t)(R0 + rr) * 512 + ((l ^ (rr & 7)) * 8),         \
                 (char*)Wl + OFF_H1S + rr * 1024);                            \
        }                                                                     \
        asm volatile("s_waitcnt vmcnt(0)" ::: "memory");                      \
        __syncthreads();                                                      \
        _Pragma("unroll")                                                     \
        for (int f = 0; f < 16; f += 2) {                                     \
            f16x8 A0 = LDH(OFF_H1S, f);                                       \
            f16x8 A1 = LDH(OFF_H1S, f + 1);                                   \
            a1a = MFMA16(A0, LDB(1, f),     a1a);                             \
            a1b = MFMA16(A1, LDB(1, f + 1), a1b);                             \
        }                                                                     \
        f32x4 acc1 = a1a + a1b;                                               \
        _Pragma("unroll")                                                     \
        for (int r = 0; r < 4; r++) {                                         \
            f16 v1 = (f16)tanh_fast(acc1[r] + bsum);                          \
            ST2x(H1o + (outrow + r) * 512 + outcolg, v1);                     \
        }                                                                     \
        asm volatile("s_waitcnt vmcnt(0)" ::: "memory");                      \
        if (l == 0) sti_s(myA, p + 1);                                        \
    }

// Fallback (2-slab h0 ring): r9's proven direct-load path, sc0 sc1 everywhere.
#define RNN_DIRECT()                                                          \
    for (int p = 0; p < 128; p++) {                                           \
        const f16* H0 = h0all + (size_t)(p & PMASK) * HSZ;                    \
        const f16* H1 = h1all + (size_t)p * HSZ;                              \
        const f16* ap = H0 + (R0 + r_lo + lr) * 512 + hi * 8;                 \
        const f16* bp = H1 + (R0 + r_lo + lr) * 512 + hi * 8;                 \
        f16* H1o = h1all + (size_t)(p + 1) * HSZ;                             \
        f16* H0o = h0all + (size_t)((p + 1) & PMASK) * HSZ;                   \
        float xprev[4];                                                       \
        _Pragma("unroll")                                                     \
        for (int r = 0; r < 4; r++) ldf_n(xprev[r], x + (outrow + r) * 128 + p); \
        if (p) { int v; for (;;) { v = ldi_s(pollB); if (__all(v >= p)) break; \
                                   __builtin_amdgcn_s_sleep(1); } }           \
        u32x4 ra0[16], ra1[16];                                               \
        __builtin_amdgcn_sched_barrier(0);                                    \
        _Pragma("unroll")                                                     \
        for (int f = 0; f < 16; f++) ld16_s(ra0[f], ap + f * 32);             \
        asm volatile("s_waitcnt vmcnt(0)" ::: "memory");                      \
        __builtin_amdgcn_sched_barrier(0);                                    \
        f32x4 z4 = {0.f, 0.f, 0.f, 0.f};                                      \
        f32x4 a0a = z4, a0b = z4, a1a = z4, a1b = z4;                         \
        _Pragma("unroll")                                                     \
        for (int f = 0; f < 16; f += 2) {                                     \
            f16x8 A0 = __builtin_bit_cast(f16x8, ra0[f]);                     \
            f16x8 A1 = __builtin_bit_cast(f16x8, ra0[f + 1]);                 \
            a0a = MFMA16(A0, bW0[f],     a0a);                                \
            a0b = MFMA16(A1, bW0[f + 1], a0b);                                \
            a1a = MFMA16(A0, LDB(0, f),     a1a);                             \
            a1b = MFMA16(A1, LDB(0, f + 1), a1b);                             \
        }                                                                     \
        f32x4 acc0 = a0a + a0b;                                               \
        _Pragma("unroll")                                                     \
        for (int r = 0; r < 4; r++) {                                         \
            f16 v0 = (f16)tanh_fast(acc0[r] + basef[r] + xprev[r] * w0);      \
            st2_s(H0o + (outrow + r) * 512 + outcolg, v0);                    \
        }                                                                     \
        asm volatile("s_waitcnt vmcnt(0)" ::: "memory");                      \
        if (l == 0) sti_s(myB, p + 1);                                        \
        if (p) { int v; for (;;) { v = ldi_s(pollA); if (__all(v >= p)) break; \
                                   __builtin_amdgcn_s_sleep(1); } }           \
        __builtin_amdgcn_sched_barrier(0);                                    \
        _Pragma("unroll")                                                     \
        for (int f = 0; f < 16; f++) ld16_s(ra1[f], bp + f * 32);             \
        asm volatile("s_waitcnt vmcnt(0)" ::: "memory");                      \
        __builtin_amdgcn_sched_barrier(0);                                    \
        _Pragma("unroll")                                                     \
        for (int f = 0; f < 16; f += 2) {                                     \
            a1a = MFMA16(__builtin_bit_cast(f16x8, ra1[f]),     LDB(1, f),     a1a); \
            a1b = MFMA16(__builtin_bit_cast(f16x8, ra1[f + 1]), LDB(1, f + 1), a1b); \
        }                                                                     \
        f32x4 acc1 = a1a + a1b;                                               \
        _Pragma("unroll")                                                     \
        for (int r = 0; r < 4; r++) {                                         \
            f16 v1 = (f16)tanh_fast(acc1[r] + bsum);                          \
            st2_s(H1o + (outrow + r) * 512 + outcolg, v1);                    \
        }                                                                     \
        asm volatile("s_waitcnt vmcnt(0)" ::: "memory");                      \
        if (l == 0) sti_s(myA, p + 1);                                        \
    }

template<bool H0F>
__global__ __launch_bounds__(256, 1) void k_rnn(
    f16* __restrict__ h0all, f16* __restrict__ h1all,
    const f16* __restrict__ Whh0h, const f16* __restrict__ Wih1h,
    const f16* __restrict__ Whh1h,
    const float* __restrict__ base, const float* __restrict__ x,
    const float* __restrict__ Wih0, const float* __restrict__ b_ih1,
    const float* __restrict__ b_hh1, int* __restrict__ slots,
    int* __restrict__ xcdtab)
{
    constexpr int PMASK = H0F ? 255 : 1;
    const int OFF_H0S = 65536, OFF_H1S = 98304;
    __shared__ __align__(16) char Wl[131072];   // 64K weights + 32K h0s + 32K h1s
    __shared__ int s_fast;
    int tid = threadIdx.x;
    int w = tid >> 6, l = tid & 63;
    int bid = blockIdx.x;
    int sub = (bid >> 3) & 1, cj = bid >> 4;
    int cluster = (bid & 7) * 2 + sub;       // cluster-mates share bid&7
    int R0 = cluster * 32, C0 = cj * 32;

    int xcdreg;
    asm("s_getreg_b32 %0, hwreg(20, 0, 4)" : "=s"(xcdreg));  // HW_REG_XCC_ID
    int my_xcd = xcdreg & 7;
    if (H0F && tid == 0) sti_s(xcdtab + (cluster * 16 + cj) * 16, my_xcd);

    // ---- stage Wih1/Whh1 col-slices into LDS with bank-conflict swizzle
    {
        const f16* srcs[2] = { Wih1h, Whh1h };
        for (int m = 0; m < 2; m++) {
            const f16* S = srcs[m] + (size_t)C0 * 512;
            for (int cch = tid; cch < 2048; cch += 256) {
                int col = cch >> 6, kc = cch & 63;
                f16x8 v = *(const f16x8*)(S + col * 512 + kc * 8);
                int byte = m * 32768 + col * 1024 + kc * 16;
                byte ^= (col & 7) << 4;
                *(f16x8*)((char*)Wl + byte) = v;
            }
        }
    }
    __syncthreads();

    int lr = l & 15, hi = l >> 4;
    int r_lo = (w >> 1) * 16, c_lo = (w & 1) * 16;
    int outrow = R0 + r_lo + hi * 4;
    int outcolg = C0 + c_lo + lr;
    int colL = c_lo + lr;
    int lrow = r_lo + lr;                 // local row within 32-row cluster
    int lrowB = lrow * 1024;
    int hi16 = hi * 16;
    int lswz = (lrow & 7) << 4;
    int cswz = (colL & 7) << 4;

    // ---- Whh0 B-fragments in registers (64 VGPR)
    f16x8 bW0[16];
    {
        const f16* w0p = Whh0h + (size_t)outcolg * 512 + hi * 8;
#pragma unroll
        for (int f = 0; f < 16; f++) bW0[f] = *(const f16x8*)(w0p + f * 32);
    }

    float basef[4];
#pragma unroll
    for (int r = 0; r < 4; r++) basef[r] = base[(outrow + r) * 512 + outcolg];
    float w0 = Wih0[outcolg * 257];
    float bsum = b_ih1[outcolg] + b_hh1[outcolg];

    // ---- per-wave slots (A = slots[0..16K), B = slots[16K..32K))
    int* slotA = slots;
    int* slotB = slots + 16384;
    int wslot = cj * 4 + w;                   // 0..63 within cluster
    int* myA = slotA + (cluster * 64 + wslot) * 16;
    int* myB = slotB + (cluster * 64 + wslot) * 16;
    const int* pollA = slotA + (cluster * 64 + l) * 16;   // lane l -> slot l
    const int* pollB = slotB + (cluster * 64 + l) * 16;

    // ---- cluster XCD-locality verification (throttled)
    bool fast = false;
    if constexpr (H0F) {
        if (w == 0) {
            int v;
            for (;;) {
                v = (l < 16) ? ldi_s(xcdtab + (cluster * 16 + l) * 16) : 0;
                if (!__any(l < 16 && v == -1)) break;
                __builtin_amdgcn_s_sleep(1);
            }
            int f = __all(l >= 16 || v == my_xcd);
            if (l == 0) s_fast = f;
        }
        __syncthreads();
        fast = (s_fast != 0);
    } else {
        if (tid == 0) s_fast = 0;
        __syncthreads();
    }

    if (H0F && fast) {
        RNN_STAGED(st2_n)      // same-XCD: shared-L2 coherent stores
    } else if (H0F) {
        RNN_STAGED(st2_s)      // virgin slabs: plain staged reads, L3 stores
    } else {
        RNN_DIRECT()           // 2-slab ring: full L3 coherence
    }
}
#undef LDH
#undef LDB

// ---------------------------------------------------------------------------
// Phase B v3 (unchanged from round 5)
__global__ __launch_bounds__(512, 2) void k_phaseB(const f16* __restrict__ h1all,
                                                   const f16* __restrict__ W1h,
                                                   const f16* __restrict__ W2h,
                                                   const float* __restrict__ b1v,
                                                   const float* __restrict__ b2,
                                                   const float* __restrict__ x,
                                                   float* __restrict__ pcontrib)
{
    __shared__ __align__(16) char Wl[108544];
    const int OFF_W2 = 65536, OFF_HID = 98304;

    int tid = threadIdx.x;
    int wv = tid >> 6, l = tid & 63;
    int lr = l & 15, hi = l >> 4;
    int M0 = blockIdx.x * 128;

    const f16* Hrow = h1all + HSZ + (size_t)(M0 + wv * 16 + lr) * 512;
    f16x8 afrag[16];
#pragma unroll
    for (int ks = 0; ks < 16; ks++)
        afrag[ks] = *(const f16x8*)(Hrow + ks * 32 + hi * 8);

    f32x4 mc[16] = {};

    {
#pragma unroll
        for (int it = 0; it < 4; it++) {
            int idx = it * 512 + tid;
            gl16(W1h + (size_t)(idx & 31) * 512 + (idx >> 5) * 8,
                 Wl + idx * 16);
        }
#pragma unroll
        for (int it = 0; it < 2; it++) {
            int idx = it * 512 + tid;
            gl16(W2h + (size_t)(idx & 255) * 2048 + (idx >> 8) * 8,
                 Wl + OFF_W2 + idx * 16);
        }
    }

    for (int c = 0; c < 64; c++) {
        int p = c & 1;
        __syncthreads();

        if (c + 1 < 64) {
            const int nc = (c + 1) * 32, q = p ^ 1;
#pragma unroll
            for (int it = 0; it < 4; it++) {
                int idx = it * 512 + tid;
                gl16(W1h + (size_t)(nc + (idx & 31)) * 512 + (idx >> 5) * 8,
                     Wl + q * 32768 + idx * 16);
            }
#pragma unroll
            for (int it = 0; it < 2; it++) {
                int idx = it * 512 + tid;
                gl16(W2h + (size_t)(idx & 255) * 2048 + nc + (idx >> 8) * 8,
                     Wl + OFF_W2 + q * 16384 + idx * 16);
            }
        }

        {
            f32x4 s3a = {0.f, 0.f, 0.f, 0.f}, s3b = s3a;
#pragma unroll
            for (int ks = 0; ks < 16; ks++) {
                f16x8 wb0 = *(const f16x8*)(Wl + p * 32768 +
                                            ((ks * 4 + hi) * 32 + lr) * 16);
                f16x8 wb1 = *(const f16x8*)(Wl + p * 32768 +
                                            ((ks * 4 + hi) * 32 + 16 + lr) * 16);
                s3a = MFMA16(afrag[ks], wb0, s3a);
                s3b = MFMA16(afrag[ks], wb1, s3b);
            }
            float bb0 = b1v[c * 32 + lr];
            float bb1 = b1v[c * 32 + 16 + lr];
#pragma unroll
            for (int r = 0; r < 4; r++) {
                int lrow = wv * 16 + hi * 4 + r;
                *(f16*)(Wl + OFF_HID + (lrow * 40 + lr) * 2) =
                    (f16)fmaxf(s3a[r] + bb0, 0.f);
                *(f16*)(Wl + OFF_HID + (lrow * 40 + 16 + lr) * 2) =
                    (f16)fmaxf(s3b[r] + bb1, 0.f);
            }
        }
        __syncthreads();

        {
            f16x8 a = *(const f16x8*)(Wl + OFF_HID +
                                      ((wv * 16 + lr) * 40 + hi * 8) * 2);
#pragma unroll
            for (int cf = 0; cf < 16; cf++) {
                f16x8 b = *(const f16x8*)(Wl + OFF_W2 + p * 16384 +
                                          (hi * 256 + cf * 16 + lr) * 16);
                mc[cf] = MFMA16(a, b, mc[cf]);
            }
        }
    }

    float quad[4] = {}, ls[4] = {}, xt[4];
#pragma unroll
    for (int r = 0; r < 4; r++) {
        int m = M0 + wv * 16 + hi * 4 + r;
        xt[r] = x[(m & 511) * 128 + (m >> 9)];
    }
#pragma unroll
    for (int cf = 0; cf < 8; cf++) {
        int cc = cf * 16 + lr;
        float bm = b2[cc], bc = b2[128 + cc];
#pragma unroll
        for (int r = 0; r < 4; r++) {
            float mean = mc[cf][r] + bm;
            float cov  = mc[cf + 8][r] + bc;
            float sp = log1pf(expf(-fabsf(cov))) + fmaxf(cov, 0.f);
            float d = xt[r] - mean;
            quad[r] += d * d * sp;
            ls[r] += logf(sp);
        }
    }
#pragma unroll
    for (int mm = 1; mm < 16; mm <<= 1)
#pragma unroll
        for (int r = 0; r < 4; r++) {
            quad[r] += __shfl_xor(quad[r], mm, 64);
            ls[r]   += __shfl_xor(ls[r], mm, 64);
        }
    if (lr == 0) {
#pragma unroll
        for (int r = 0; r < 4; r++) {
            int m = M0 + wv * 16 + hi * 4 + r;
            pcontrib[m] = -0.5f * (LOGDET_C + quad[r]) - 0.5f * ls[r];
        }
    }
}

// ---------------------------------------------------------------------------
__global__ void k_fin(const f16* __restrict__ h1last,
                      const float* __restrict__ pcontrib, float* __restrict__ out)
{
    int gid = blockIdx.x * 256 + threadIdx.x;
    for (int i = gid; i < HSZ; i += 131072) out[i] = (float)h1last[i];
    if (gid < 512) {
        float s = 0.f;
        for (int tt = 0; tt < 128; tt++) s += pcontrib[tt * 512 + gid];
        out[HSZ + gid] = s;
    }
}

// ---------------------------------------------------------------------------
extern "C" void kernel_launch(void* const* d_in, const int* in_sizes, int n_in,
                              void* d_out, int out_size, void* d_ws, size_t ws_size,
                              hipStream_t stream) {
    const float* x     = (const float*)d_in[0];
    const float* mask  = (const float*)d_in[1];
    const float* Wih0  = (const float*)d_in[2];
    const float* Whh0  = (const float*)d_in[3];
    const float* b_ih0 = (const float*)d_in[4];
    const float* b_hh0 = (const float*)d_in[5];
    const float* Wih1  = (const float*)d_in[6];
    const float* Whh1  = (const float*)d_in[7];
    const float* b_ih1 = (const float*)d_in[8];
    const float* b_hh1 = (const float*)d_in[9];
    const float* W1    = (const float*)d_in[10];
    const float* b1    = (const float*)d_in[11];
    const float* W2    = (const float*)d_in[12];
    const float* b2    = (const float*)d_in[13];

    char* ws = (char*)d_ws;
    size_t off = 0;
    auto take = [&](size_t bytes) { char* p = ws + off; off += (bytes + 255) & ~(size_t)255; return p; };
    float* base    = (float*)take(512 * 512 * 4);
    f16* Whh0h     = (f16*)take(HSZ * 2);
    f16* Wih1h     = (f16*)take(HSZ * 2);
    f16* Whh1h     = (f16*)take(HSZ * 2);
    f16* W1h       = (f16*)take(1048576 * 2);
    f16* W2h       = (f16*)take(524288 * 2);
    f16* h0buf     = (f16*)take(2 * HSZ * 2);
    f16* h1all     = (f16*)take((size_t)129 * HSZ * 2);
    float* pcontrib= (float*)take(128 * 512 * 4);
    f16* A         = (f16*)take(65536 * 2);
    f16* B1        = (f16*)take(65536 * 2);
    float* biasv   = (float*)take(512 * 4);
    int* slots     = (int*)take(32768 * 4);
    int* xcdtab    = (int*)take(4096 * 4);
    if (off > ws_size) return;

    // Optional monotonic h0 slabs (66 MB): enables cached/virgin h0 reads.
    const size_t h0all_bytes = (size_t)129 * HSZ * 2;
    bool big = (off + h0all_bytes + 256 <= ws_size);
    f16* h0all = big ? (f16*)take(h0all_bytes) : h0buf;

    k_conv<<<256, 256, 0, stream>>>(x, mask, Wih0, b_ih0, b_hh0, Whh0, Wih1, Whh1,
                                    W1, W2, A, B1, biasv, Whh0h, Wih1h, Whh1h,
                                    W1h, W2h, h1all, slots, xcdtab);
    k_base<<<256, 256, 0, stream>>>(A, B1, biasv, base, h0all);
    if (big)
        k_rnn<true><<<256, 256, 0, stream>>>(h0all, h1all, Whh0h, Wih1h, Whh1h,
                                             base, x, Wih0, b_ih1, b_hh1, slots,
                                             xcdtab);
    else
        k_rnn<false><<<256, 256, 0, stream>>>(h0all, h1all, Whh0h, Wih1h, Whh1h,
                                              base, x, Wih0, b_ih1, b_hh1, slots,
                                              xcdtab);
    k_phaseB<<<512, 512, 0, stream>>>(h1all, W1h, W2h, b1, b2, x, pcontrib);
    k_fin<<<512, 256, 0, stream>>>(h1all + (size_t)128 * HSZ, pcontrib, (float*)d_out);
}